// Round 1
// baseline (1603.591 us; speedup 1.0000x reference)
//
#include <hip/hip_runtime.h>
#include <hip/hip_bf16.h>
#include <stdint.h>

#define TOK  4096
#define DIM  2048
#define HID  4096
#define ODIM 2048
#define NEXP 8
#define KSEL 5
#define KTOT (NEXP * HID)   // 32768

typedef __bf16 bf16x8 __attribute__((ext_vector_type(8)));
typedef float  f32x4  __attribute__((ext_vector_type(4)));

__device__ __forceinline__ uint16_t f2bf(float f) {
  uint32_t u = __float_as_uint(f);
  u += 0x7FFFu + ((u >> 16) & 1u);   // round-to-nearest-even
  return (uint16_t)(u >> 16);
}

#define GLD16(g, l) __builtin_amdgcn_global_load_lds(                      \
    (const __attribute__((address_space(1))) void*)(g),                    \
    (__attribute__((address_space(3))) void*)(l), 16, 0, 0)

// ---------------- convert kernels ----------------

__global__ void cast_x_kernel(const float* __restrict__ in,
                              uint16_t* __restrict__ out, int n4) {
  int i = blockIdx.x * blockDim.x + threadIdx.x;
  if (i >= n4) return;
  float4 v = ((const float4*)in)[i];
  ushort4 o;
  o.x = f2bf(v.x); o.y = f2bf(v.y); o.z = f2bf(v.z); o.w = f2bf(v.w);
  ((ushort4*)out)[i] = o;
}

// out[c*R + r] = bf16(in[r*C + c]), batched over blockIdx.z
__global__ void transpose_cast_kernel(const float* __restrict__ in,
                                      uint16_t* __restrict__ out,
                                      int R, int C, long inBatch, long outBatch) {
  __shared__ float tile[32][33];
  const float* src = in + (size_t)blockIdx.z * inBatch;
  uint16_t*    dst = out + (size_t)blockIdx.z * outBatch;
  int c0 = blockIdx.x * 32, r0 = blockIdx.y * 32;
  int tx = threadIdx.x, ty = threadIdx.y;   // (32, 8)
#pragma unroll
  for (int i = 0; i < 4; ++i)
    tile[ty + i * 8][tx] = src[(size_t)(r0 + ty + i * 8) * C + c0 + tx];
  __syncthreads();
#pragma unroll
  for (int i = 0; i < 4; ++i)
    dst[(size_t)(c0 + ty + i * 8) * R + r0 + tx] = f2bf(tile[tx][ty + i * 8]);
}

// ---------------- routing ----------------

__global__ void routing_kernel(const float* __restrict__ x,
                               const float* __restrict__ Wg, const float* __restrict__ bg,
                               const float* __restrict__ Wa, const float* __restrict__ ba,
                               const float* __restrict__ Wb, const float* __restrict__ bb,
                               const float* __restrict__ sigs,
                               float* __restrict__ wts) {
  const int n    = blockIdx.x;
  const int lane = threadIdx.x;   // 64
  const float* xr = x + (size_t)n * DIM;

  float ga[NEXP]; float aa[32];
#pragma unroll
  for (int e = 0; e < NEXP; ++e) ga[e] = 0.f;
#pragma unroll
  for (int j = 0; j < 32; ++j) aa[j] = 0.f;

  for (int it = 0; it < DIM / 64; ++it) {
    int d = it * 64 + lane;
    float xv = xr[d];
    const float* wgr = Wg + (size_t)d * NEXP;
#pragma unroll
    for (int e = 0; e < NEXP; ++e) ga[e] += xv * wgr[e];
    const float* war = Wa + (size_t)d * 32;
#pragma unroll
    for (int j = 0; j < 32; ++j) aa[j] += xv * war[j];
  }
#pragma unroll
  for (int s = 1; s < 64; s <<= 1) {
#pragma unroll
    for (int e = 0; e < NEXP; ++e) ga[e] += __shfl_xor(ga[e], s);
#pragma unroll
    for (int j = 0; j < 32; ++j) aa[j] += __shfl_xor(aa[j], s);
  }

  // ph = relu(a) @ Wb + bb
  float ph[16];
#pragma unroll
  for (int i = 0; i < 16; ++i) ph[i] = bb[i];
#pragma unroll
  for (int j = 0; j < 32; ++j) {
    float a = aa[j] + ba[j];
    a = a > 0.f ? a : 0.f;
#pragma unroll
    for (int i = 0; i < 16; ++i) ph[i] += a * Wb[j * 16 + i];
  }
  float nrm = 0.f;
#pragma unroll
  for (int i = 0; i < 16; ++i) nrm += ph[i] * ph[i];
  nrm = fmaxf(sqrtf(nrm), 1e-12f);

  const float invT = 0.36787944117144233f;  // 1/e
  float lg[NEXP], mx = -1e30f;
#pragma unroll
  for (int e = 0; e < NEXP; ++e) { lg[e] = (ga[e] + bg[e]) * invT; mx = fmaxf(mx, lg[e]); }
  float psum = 0.f, pr[NEXP];
#pragma unroll
  for (int e = 0; e < NEXP; ++e) { pr[e] = expf(lg[e] - mx); psum += pr[e]; }

  float eff[NEXP];
#pragma unroll
  for (int e = 0; e < NEXP; ++e) {
    const float* sg = sigs + e * 16;
    float dot = 0.f, sn = 0.f;
#pragma unroll
    for (int i = 0; i < 16; ++i) { dot += ph[i] * sg[i]; sn += sg[i] * sg[i]; }
    sn = fmaxf(sqrtf(sn), 1e-12f);
    float match = (dot / (nrm * sn) + 1.f) * 0.5f;
    eff[e] = (pr[e] / psum) * match;
  }

  // top-5 (ties -> lowest index first, matches lax.top_k)
  int selmask = 0;
#pragma unroll
  for (int t = 0; t < KSEL; ++t) {
    int bi = 0; float bv = -1e30f;
#pragma unroll
    for (int e = 0; e < NEXP; ++e) {
      bool ok = !((selmask >> e) & 1);
      if (ok && eff[e] > bv) { bv = eff[e]; bi = e; }
    }
    selmask |= (1 << bi);
  }
  float wsum = 0.f, wv[NEXP];
#pragma unroll
  for (int e = 0; e < NEXP; ++e) {
    wv[e] = ((selmask >> e) & 1) ? eff[e] : 0.f;
    wsum += wv[e];
  }
  float inv = 1.f / (wsum + 1e-8f);
  if (lane == 0) {
#pragma unroll
    for (int e = 0; e < NEXP; ++e) wts[n * NEXP + e] = wv[e] * inv;
  }
}

// ---------------- GEMM (A [M,K] row-major bf16, Bt [N,K] row-major bf16) ----------------
// MODE 1: C = w[n,e] * relu(A@B + b1[e]) -> bf16 hbuf[row*KTOT + e*HID + col]
// MODE 2: C = A@B + sum_e w[n,e]*b2[e, col] -> f32 out[row*ODIM + col]

template <int MODE>
__global__ void gemm_bt_kernel(const uint16_t* __restrict__ A,
                               const uint16_t* __restrict__ Bt,
                               int M, int Nloc, int K,
                               const float* __restrict__ wts,
                               const float* __restrict__ bias,
                               uint16_t* __restrict__ outBf,
                               float* __restrict__ outF) {
  __shared__ __attribute__((aligned(16))) uint16_t smA[128 * 64];
  __shared__ __attribute__((aligned(16))) uint16_t smB[128 * 64];
  const int e     = blockIdx.z;
  const uint16_t* Bte = Bt + (size_t)e * Nloc * K;
  const int tileM = blockIdx.y * 128;
  const int tileN = blockIdx.x * 128;
  const int tid  = threadIdx.x;
  const int lane = tid & 63;
  const int wid  = tid >> 6;
  const int wr = wid >> 1, wc = wid & 1;

  f32x4 acc[4][4];
#pragma unroll
  for (int m = 0; m < 4; ++m)
#pragma unroll
    for (int n = 0; n < 4; ++n)
      acc[m][n] = (f32x4){0.f, 0.f, 0.f, 0.f};

  for (int k0 = 0; k0 < K; k0 += 64) {
    // stage A,B tiles: linear LDS dest, XOR-swizzled global source (granule = 16B = 8 bf16)
#pragma unroll
    for (int j = 0; j < 4; ++j) {
      const int f   = (wid * 4 + j) * 64 + lane;   // granule id 0..1023
      const int row = f >> 3;
      const int s8  = (f & 7) ^ (row & 7);
      GLD16(A   + (size_t)(tileM + row) * K + k0 + s8 * 8, (char*)smA + (wid * 4 + j) * 1024);
      GLD16(Bte + (size_t)(tileN + row) * K + k0 + s8 * 8, (char*)smB + (wid * 4 + j) * 1024);
    }
    __syncthreads();

#pragma unroll
    for (int kk = 0; kk < 2; ++kk) {
      bf16x8 av[4], bv[4];
#pragma unroll
      for (int m = 0; m < 4; ++m) {
        const int row = wr * 64 + m * 16 + (lane & 15);
        const int g   = (kk * 4 + (lane >> 4)) ^ (row & 7);
        av[m] = *(const bf16x8*)(smA + row * 64 + g * 8);
      }
#pragma unroll
      for (int n = 0; n < 4; ++n) {
        const int row = wc * 64 + n * 16 + (lane & 15);
        const int g   = (kk * 4 + (lane >> 4)) ^ (row & 7);
        bv[n] = *(const bf16x8*)(smB + row * 64 + g * 8);
      }
#pragma unroll
      for (int m = 0; m < 4; ++m)
#pragma unroll
        for (int n = 0; n < 4; ++n)
          acc[m][n] = __builtin_amdgcn_mfma_f32_16x16x32_bf16(av[m], bv[n], acc[m][n], 0, 0, 0);
    }
    __syncthreads();
  }

  if (MODE == 1) {
    float wv[4][4];
#pragma unroll
    for (int m = 0; m < 4; ++m)
#pragma unroll
      for (int r = 0; r < 4; ++r) {
        const int row = tileM + wr * 64 + m * 16 + ((lane >> 4) << 2) + r;
        wv[m][r] = wts[row * NEXP + e];
      }
    const float* be = bias + (size_t)e * Nloc;
#pragma unroll
    for (int n = 0; n < 4; ++n) {
      const int col  = tileN + wc * 64 + n * 16 + (lane & 15);
      const float bc = be[col];
#pragma unroll
      for (int m = 0; m < 4; ++m)
#pragma unroll
        for (int r = 0; r < 4; ++r) {
          const int row = tileM + wr * 64 + m * 16 + ((lane >> 4) << 2) + r;
          float v = acc[m][n][r] + bc;
          v = v > 0.f ? v : 0.f;
          v *= wv[m][r];
          outBf[(size_t)row * KTOT + (size_t)e * HID + col] = f2bf(v);
        }
    }
  } else {
#pragma unroll
    for (int m = 0; m < 4; ++m)
#pragma unroll
      for (int r = 0; r < 4; ++r) {
        const int row = tileM + wr * 64 + m * 16 + ((lane >> 4) << 2) + r;
        const float* w8 = wts + row * NEXP;
        float w[8];
#pragma unroll
        for (int q = 0; q < 8; ++q) w[q] = w8[q];
#pragma unroll
        for (int n = 0; n < 4; ++n) {
          const int col = tileN + wc * 64 + n * 16 + (lane & 15);
          float s = acc[m][n][r];
#pragma unroll
          for (int q = 0; q < 8; ++q) s += w[q] * bias[q * ODIM + col];
          outF[(size_t)row * ODIM + col] = s;
        }
      }
  }
}

// ---------------- launch ----------------

extern "C" void kernel_launch(void* const* d_in, const int* in_sizes, int n_in,
                              void* d_out, int out_size, void* d_ws, size_t ws_size,
                              hipStream_t stream) {
  const float* x    = (const float*)d_in[0];
  const float* Wg   = (const float*)d_in[1];
  const float* bg   = (const float*)d_in[2];
  const float* Wa   = (const float*)d_in[3];
  const float* ba   = (const float*)d_in[4];
  const float* Wb   = (const float*)d_in[5];
  const float* bb   = (const float*)d_in[6];
  const float* sigs = (const float*)d_in[7];
  const float* W1   = (const float*)d_in[8];
  const float* b1   = (const float*)d_in[9];
  const float* W2   = (const float*)d_in[10];
  const float* b2   = (const float*)d_in[11];
  float* out = (float*)d_out;

  char* ws = (char*)d_ws;
  // offsets (bytes), 256-aligned
  float*    wts  = (float*)(ws + 0);            // 4096*8*4      =    131072
  uint16_t* xbf  = (uint16_t*)(ws + 131072);    // 4096*2048*2   =  16777216
  uint16_t* W1T  = (uint16_t*)(ws + 16908288);  // 8*4096*2048*2 = 134217728
  uint16_t* W2T  = (uint16_t*)(ws + 151126016); // 2048*32768*2  = 134217728
  uint16_t* hbuf = (uint16_t*)(ws + 285343744); // 4096*32768*2  = 268435456
  // total: 553779200 bytes

  cast_x_kernel<<<(TOK * DIM / 4) / 256, 256, 0, stream>>>(x, xbf, TOK * DIM / 4);
  transpose_cast_kernel<<<dim3(HID / 32, DIM / 32, NEXP), dim3(32, 8), 0, stream>>>(
      W1, W1T, DIM, HID, (long)DIM * HID, (long)DIM * HID);
  transpose_cast_kernel<<<dim3(ODIM / 32, KTOT / 32, 1), dim3(32, 8), 0, stream>>>(
      W2, W2T, KTOT, ODIM, 0, 0);
  routing_kernel<<<TOK, 64, 0, stream>>>(x, Wg, bg, Wa, ba, Wb, bb, sigs, wts);

  gemm_bt_kernel<1><<<dim3(HID / 128, TOK / 128, NEXP), 256, 0, stream>>>(
      xbf, W1T, TOK, HID, DIM, wts, b1, hbuf, nullptr);
  gemm_bt_kernel<2><<<dim3(ODIM / 128, TOK / 128, 1), 256, 0, stream>>>(
      hbuf, W2T, TOK, ODIM, KTOT, wts, b2, nullptr, out);
}